// Round 11
// baseline (105.551 us; speedup 1.0000x reference)
//
#include <hip/hip_runtime.h>

#define BB 262144
#define TT 20
#define HH 10

static constexpr float L2E = 1.44269504088896340736f;

typedef float    f16v __attribute__((ext_vector_type(16)));
typedef _Float16 h8   __attribute__((ext_vector_type(8)));

#define MFMA32(A, B, C) __builtin_amdgcn_mfma_f32_32x32x16_f16((A), (B), (C), 0, 0, 0)

__device__ __forceinline__ float frcp(float x)  { return __builtin_amdgcn_rcpf(x); }
__device__ __forceinline__ float fexp2(float x) { return __builtin_amdgcn_exp2f(x); }

// 32x32x16 layout, one wave = 32 sequences (cols). Row map (verified C rule:
// row=(reg&3)+8*(reg>>2)+4*(lane>>5)): gate e of slot sigma=(tile*4+q) on half
// hi lives at row e+8q+4hi, acc[tile][4q+e]. Slots: hi=0 sigma0..4 = units 0..4;
// hi=1 sigma0..4 = units 5..9, sigma5 = head a0..a3, sigma6 = head a4.
// A rows prescaled: gates i,f,o by -L2E, g by +2*L2E; head rows raw.
// B (col=l&31, k=8*(l>>5)+j): k0..9=h0..h9, k10=1, k11=x, k12..15=dc (A==0).
// h5,h6,h7 cross halves via 3x shfl_xor(32). All 5 ACT slots are real units.

#define ACT(GI, GF, GG, GO, CC, HN) { \
        const float ei  = fexp2(GI); \
        const float ef  = fexp2(GF); \
        const float eg2 = fexp2(GG); \
        const float eo  = fexp2(GO); \
        const float t1 = 1.0f + ef, t2 = 1.0f + ei; \
        const float t3 = eg2 + 1.0f, t4 = eg2 - 1.0f; \
        const float t5 = t2 * t3; \
        const float cn = fmaf((CC), t5, t4 * t1) * frcp(t1 * t5); \
        (CC) = cn; \
        const float ec = fexp2(cn * (2.0f * L2E)); \
        (HN) = (ec - 1.0f) * frcp((1.0f + eo) * (ec + 1.0f)); \
    }

#define STEP(XT, SREF) { \
        const float r5 = __shfl_xor(hn0, 32, 64); \
        const float r6 = __shfl_xor(hn1, 32, 64); \
        const float r7 = __shfl_xor(hn2, 32, 64); \
        const float sA = hi1 ? hn3 : hn0; \
        const float sB = hi1 ? hn4 : hn1; \
        const float sC = hi1 ? 1.0f : hn2; \
        const float sD = hi1 ? (XT) : hn3; \
        h8 Bf; \
        Bf[0] = (_Float16)sA;  Bf[1] = (_Float16)sB; \
        Bf[2] = (_Float16)sC;  Bf[3] = (_Float16)sD; \
        Bf[4] = (_Float16)hn4; Bf[5] = (_Float16)r5; \
        Bf[6] = (_Float16)r6;  Bf[7] = (_Float16)r7; \
        const f16v z16 = {0,0,0,0,0,0,0,0,0,0,0,0,0,0,0,0}; \
        f16v A0 = MFMA32(Af0, Bf, z16); \
        f16v A1 = MFMA32(Af1, Bf, z16); \
        { \
            float zz = b2p; \
            float q0 = A1[4]; q0 = fmaxf(q0, 0.2f * q0); zz = fmaf(q0, w2p0, zz); \
            float q1 = A1[5]; q1 = fmaxf(q1, 0.2f * q1); zz = fmaf(q1, w2p1, zz); \
            float q2 = A1[6]; q2 = fmaxf(q2, 0.2f * q2); zz = fmaf(q2, w2p2, zz); \
            float q3 = A1[7]; q3 = fmaxf(q3, 0.2f * q3); zz = fmaf(q3, w2p3, zz); \
            float q4 = A1[8]; q4 = fmaxf(q4, 0.2f * q4); zz = fmaf(q4, w2p4, zz); \
            (SREF) = frcp(1.0f + fexp2(zz)); \
        } \
        ACT(A0[0],  A0[1],  A0[2],  A0[3],  c0, hn0) \
        ACT(A0[4],  A0[5],  A0[6],  A0[7],  c1, hn1) \
        ACT(A0[8],  A0[9],  A0[10], A0[11], c2, hn2) \
        ACT(A0[12], A0[13], A0[14], A0[15], c3, hn3) \
        ACT(A1[0],  A1[1],  A1[2],  A1[3],  c4, hn4) \
    }

__global__ __launch_bounds__(256) void lstm_disc_mfma32(
    const float* __restrict__ values, const float* __restrict__ masks,
    const float* __restrict__ W_ih, const float* __restrict__ W_hh,
    const float* __restrict__ b_ih, const float* __restrict__ b_hh,
    const float* __restrict__ W1, const float* __restrict__ b1,
    const float* __restrict__ W2, const float* __restrict__ b2,
    const int* __restrict__ directp,
    float* __restrict__ out)
{
    const int tid  = threadIdx.x;
    const int l    = tid & 63;
    const int col  = l & 31;
    const bool hi1 = (l >> 5) != 0;
    const int gw   = blockIdx.x * 4 + (tid >> 6);
    const int seq  = gw * 32 + col;
    const int dir  = *directp;

    // ---- build A fragments once ----
    h8 Af0, Af1;
    {
        const int r    = l & 31;       // A row
        const int e    = r & 3;        // gate index / head row
        const int hi_r = (r >> 2) & 1; // which half owns this row's slot
        const int q    = r >> 3;       // within-tile slot
        const int kb   = (l >> 5) * 8; // k-window base
        h8* afp[2] = {&Af0, &Af1};
        #pragma unroll
        for (int tile = 0; tile < 2; ++tile) {
            const int sig = tile * 4 + q;
            int u;  // >=0: unit; -1: headA; -2: headB; -3: zero row
            if (hi_r == 0) u = (sig <= 4) ? sig : -3;
            else           u = (sig <= 4) ? 5 + sig : ((sig == 5) ? -1 : ((sig == 6) ? -2 : -3));
            float tmp[8];
            #pragma unroll
            for (int j = 0; j < 8; ++j) {
                const int k = kb + j;
                float v = 0.0f;
                if (u >= 0) {
                    const int orow = 10 * e + u;  // gate e of unit u
                    if (k < 10)       v = W_hh[orow * 10 + k];
                    else if (k == 10) v = b_ih[orow] + b_hh[orow];
                    else if (k == 11) v = W_ih[orow];
                    v *= (e == 2) ? (2.0f * L2E) : (-L2E);
                } else if (u == -1) {
                    if (k < 10)       v = W1[e * 10 + k];
                    else if (k == 10) v = b1[e];
                } else if (u == -2) {
                    if (e == 0) {
                        if (k < 10)       v = W1[40 + k];
                        else if (k == 10) v = b1[4];
                    }
                }
                tmp[j] = v;
            }
            h8 a;
            #pragma unroll
            for (int j = 0; j < 8; ++j) a[j] = (_Float16)tmp[j];
            *afp[tile] = a;
        }
    }

    // ---- sequence values (2x redundant across halves; L1 serves) ----
    float vals[TT];
    {
        const float4* vrow = reinterpret_cast<const float4*>(values + (size_t)seq * TT);
        #pragma unroll
        for (int i = 0; i < TT / 4; ++i) {
            float4 v = vrow[i];
            vals[4 * i + 0] = v.x; vals[4 * i + 1] = v.y;
            vals[4 * i + 2] = v.z; vals[4 * i + 3] = v.w;
        }
        if (dir != 0) {
            #pragma unroll
            for (int i = 0; i < TT / 2; ++i) {
                float tmp = vals[i]; vals[i] = vals[TT - 1 - i]; vals[TT - 1 - i] = tmp;
            }
        }
    }

    // head scalars, prescaled (wave-uniform -> SGPR)
    const float w2p0 = -L2E * W2[0], w2p1 = -L2E * W2[1], w2p2 = -L2E * W2[2],
                w2p3 = -L2E * W2[3], w2p4 = -L2E * W2[4];
    const float b2p = -L2E * b2[0];

    float hn0 = 0.f, hn1 = 0.f, hn2 = 0.f, hn3 = 0.f, hn4 = 0.f;
    float c0 = 0.f, c1 = 0.f, c2 = 0.f, c3 = 0.f, c4 = 0.f;
    float sc[TT];

    #pragma unroll
    for (int t = 0; t < TT; ++t) {
        STEP(vals[t], sc[t])
    }

    // ---- scores: hi=1 lanes own their column's score row ----
    if (hi1) {
        float4* o4 = reinterpret_cast<float4*>(out + (size_t)seq * TT);
        #pragma unroll
        for (int i = 0; i < TT / 4; ++i) {
            float4 v;
            v.x = sc[4 * i + 0]; v.y = sc[4 * i + 1];
            v.z = sc[4 * i + 2]; v.w = sc[4 * i + 3];
            o4[i] = v;
        }
    } else {
        // ---- masks pass-through: hi=0 lanes ----
        const float* mrow = masks + (size_t)seq * TT;
        float* mout = out + (size_t)BB * TT + (size_t)seq * TT;
        if (dir == 0) {
            const float4* m4 = (const float4*)mrow;
            float4* o4 = (float4*)mout;
            #pragma unroll
            for (int i = 0; i < TT / 4; ++i) o4[i] = m4[i];
        } else {
            #pragma unroll
            for (int t = 0; t < TT; ++t) mout[t] = mrow[TT - 1 - t];
        }
    }
}

extern "C" void kernel_launch(void* const* d_in, const int* in_sizes, int n_in,
                              void* d_out, int out_size, void* d_ws, size_t ws_size,
                              hipStream_t stream) {
    const float* values = (const float*)d_in[0];
    const float* masks  = (const float*)d_in[1];
    const float* W_ih   = (const float*)d_in[2];
    const float* W_hh   = (const float*)d_in[3];
    const float* b_ih   = (const float*)d_in[4];
    const float* b_hh   = (const float*)d_in[5];
    const float* W1     = (const float*)d_in[6];
    const float* b1     = (const float*)d_in[7];
    const float* W2     = (const float*)d_in[8];
    const float* b2     = (const float*)d_in[9];
    const int*   direct = (const int*)d_in[11];
    float* out = (float*)d_out;

    // 32 sequences per wave, 4 waves per block -> 128 seqs/block
    const int block = 256;
    const int grid = BB / 128;   // 2048 blocks -> 8192 waves -> 262144 seqs
    lstm_disc_mfma32<<<grid, block, 0, stream>>>(values, masks, W_ih, W_hh, b_ih, b_hh,
                                                 W1, b1, W2, b2, direct, out);
}

// Round 12
// 59.199 us; speedup vs baseline: 1.7830x; 1.7830x over previous
//
#include <hip/hip_runtime.h>

#define BB 262144
#define TT 20
#define HH 10

static constexpr float L2E = 1.44269504088896340736f;
static constexpr float K2  = 2.0f * L2E;

typedef float    f16v __attribute__((ext_vector_type(16)));
typedef _Float16 h8   __attribute__((ext_vector_type(8)));
typedef __fp16   q2   __attribute__((ext_vector_type(2)));
typedef __fp16   q4   __attribute__((ext_vector_type(4)));
typedef __fp16   q8   __attribute__((ext_vector_type(8)));

#define MFMA32(A, B, C) __builtin_amdgcn_mfma_f32_32x32x16_f16((A), (B), (C), 0, 0, 0)

__device__ __forceinline__ float frcp(float x)  { return __builtin_amdgcn_rcpf(x); }
__device__ __forceinline__ float fexp2(float x) { return __builtin_amdgcn_exp2f(x); }

// Layout identical to R11 (validated, absmax 0.0039):
//   one wave = 32 sequences (C cols). Row r = e + 4*hi_r + 8*q; slot sigma = tile*4+q.
//   hi_r=0: sigma0..4 = units 0..4; hi_r=1: sigma0..4 = units 5..9, sigma5 = head
//   a0..a3, sigma6 = head a4 (e==0). A gate rows prescaled i,f,o: -L2E, g: +2*L2E.
//   B (col=l&31, k=8*(l>>5)+j): k0..9 = h0..h9, k10 = 1, k11 = x, k12..15 = dc (A==0).
//   h5,h6,h7 return to the lo half via 3x shfl_xor(32). All 5 ACT slots are real.
// R12 changes: streamed values/scores (no vals[20]/sc[20]), rolled outer chunk loop,
// c-state pre-scaled by 2*L2E, pkrtz packed B-build, waves_per_eu(4,8).

// ACT with pre-scaled cell state CP = 2*L2E*c:
//   cnP = [CP*t5 + t4k*t1] / (t1*t5),  t4k = 2L2E*(eg2-1) = fma(eg2,K2,-K2)
#define ACT(GI, GF, GG, GO, CP, HN) { \
        const float ei  = fexp2(GI); \
        const float ef  = fexp2(GF); \
        const float eg2 = fexp2(GG); \
        const float eo  = fexp2(GO); \
        const float t1 = 1.0f + ef, t2 = 1.0f + ei; \
        const float t3 = eg2 + 1.0f; \
        const float t4k = fmaf(eg2, K2, -K2); \
        const float t5 = t2 * t3; \
        const float cnp = fmaf((CP), t5, t4k * t1) * frcp(t1 * t5); \
        (CP) = cnp; \
        const float ec = fexp2(cnp); \
        (HN) = (ec - 1.0f) * frcp((1.0f + eo) * (ec + 1.0f)); \
    }

#define STEP(XT, SREF) { \
        const float r5 = __shfl_xor(hn0, 32, 64); \
        const float r6 = __shfl_xor(hn1, 32, 64); \
        const float r7 = __shfl_xor(hn2, 32, 64); \
        const float sA = hi1 ? hn3 : hn0; \
        const float sB = hi1 ? hn4 : hn1; \
        const float sC = hi1 ? 1.0f : hn2; \
        const float sD = hi1 ? (XT) : hn3; \
        const q2 p0 = __builtin_amdgcn_cvt_pkrtz(sA, sB); \
        const q2 p1 = __builtin_amdgcn_cvt_pkrtz(sC, sD); \
        const q2 p2 = __builtin_amdgcn_cvt_pkrtz(hn4, r5); \
        const q2 p3 = __builtin_amdgcn_cvt_pkrtz(r6, r7); \
        const q4 lo4 = __builtin_shufflevector(p0, p1, 0, 1, 2, 3); \
        const q4 hi4 = __builtin_shufflevector(p2, p3, 0, 1, 2, 3); \
        const q8 w8  = __builtin_shufflevector(lo4, hi4, 0, 1, 2, 3, 4, 5, 6, 7); \
        const h8 Bf  = __builtin_bit_cast(h8, w8); \
        const f16v z16 = {0,0,0,0,0,0,0,0,0,0,0,0,0,0,0,0}; \
        f16v A0 = MFMA32(Af0, Bf, z16); \
        f16v A1 = MFMA32(Af1, Bf, z16); \
        { \
            float zz = b2p; \
            float u0 = A1[4]; u0 = fmaxf(u0, 0.2f * u0); zz = fmaf(u0, w2p0, zz); \
            float u1 = A1[5]; u1 = fmaxf(u1, 0.2f * u1); zz = fmaf(u1, w2p1, zz); \
            float u2 = A1[6]; u2 = fmaxf(u2, 0.2f * u2); zz = fmaf(u2, w2p2, zz); \
            float u3 = A1[7]; u3 = fmaxf(u3, 0.2f * u3); zz = fmaf(u3, w2p3, zz); \
            float u4 = A1[8]; u4 = fmaxf(u4, 0.2f * u4); zz = fmaf(u4, w2p4, zz); \
            (SREF) = frcp(1.0f + fexp2(zz)); \
        } \
        ACT(A0[0],  A0[1],  A0[2],  A0[3],  cp0, hn0) \
        ACT(A0[4],  A0[5],  A0[6],  A0[7],  cp1, hn1) \
        ACT(A0[8],  A0[9],  A0[10], A0[11], cp2, hn2) \
        ACT(A0[12], A0[13], A0[14], A0[15], cp3, hn3) \
        ACT(A1[0],  A1[1],  A1[2],  A1[3],  cp4, hn4) \
    }

__device__ __forceinline__ float4 rev4(float4 v) {
    float4 r; r.x = v.w; r.y = v.z; r.z = v.y; r.w = v.x; return r;
}

__global__ __launch_bounds__(256)
__attribute__((amdgpu_waves_per_eu(4, 8)))
void lstm_disc_mfma32(
    const float* __restrict__ values, const float* __restrict__ masks,
    const float* __restrict__ W_ih, const float* __restrict__ W_hh,
    const float* __restrict__ b_ih, const float* __restrict__ b_hh,
    const float* __restrict__ W1, const float* __restrict__ b1,
    const float* __restrict__ W2, const float* __restrict__ b2,
    const int* __restrict__ directp,
    float* __restrict__ out)
{
    const int tid  = threadIdx.x;
    const int l    = tid & 63;
    const int col  = l & 31;
    const bool hi1 = (l >> 5) != 0;
    const int gw   = blockIdx.x * 4 + (tid >> 6);
    const int seq  = gw * 32 + col;
    const int dir  = *directp;

    // ---- build A fragments once (same as R11) ----
    h8 Af0, Af1;
    {
        const int r    = l & 31;       // A row
        const int e    = r & 3;        // gate index / head row
        const int hi_r = (r >> 2) & 1; // slot half
        const int q    = r >> 3;       // within-tile slot
        const int kb   = (l >> 5) * 8; // k-window base
        h8* afp[2] = {&Af0, &Af1};
        #pragma unroll
        for (int tile = 0; tile < 2; ++tile) {
            const int sig = tile * 4 + q;
            int u;  // >=0: unit; -1: headA; -2: headB; -3: zero row
            if (hi_r == 0) u = (sig <= 4) ? sig : -3;
            else           u = (sig <= 4) ? 5 + sig : ((sig == 5) ? -1 : ((sig == 6) ? -2 : -3));
            float tmp[8];
            #pragma unroll
            for (int j = 0; j < 8; ++j) {
                const int k = kb + j;
                float v = 0.0f;
                if (u >= 0) {
                    const int orow = 10 * e + u;
                    if (k < 10)       v = W_hh[orow * 10 + k];
                    else if (k == 10) v = b_ih[orow] + b_hh[orow];
                    else if (k == 11) v = W_ih[orow];
                    v *= (e == 2) ? (2.0f * L2E) : (-L2E);
                } else if (u == -1) {
                    if (k < 10)       v = W1[e * 10 + k];
                    else if (k == 10) v = b1[e];
                } else if (u == -2) {
                    if (e == 0) {
                        if (k < 10)       v = W1[40 + k];
                        else if (k == 10) v = b1[4];
                    }
                }
                tmp[j] = v;
            }
            h8 a;
            #pragma unroll
            for (int j = 0; j < 8; ++j) a[j] = (_Float16)tmp[j];
            *afp[tile] = a;
        }
    }

    // head scalars, prescaled (wave-uniform -> SGPR)
    const float w2p0 = -L2E * W2[0], w2p1 = -L2E * W2[1], w2p2 = -L2E * W2[2],
                w2p3 = -L2E * W2[3], w2p4 = -L2E * W2[4];
    const float b2p = -L2E * b2[0];

    // ---- streamed values: float4 chunks, one-ahead prefetch (hi1 lanes feed x) ----
    const float4* vr = reinterpret_cast<const float4*>(values + (size_t)seq * TT);
    float4 cur = {0.f, 0.f, 0.f, 0.f}, nxt = {0.f, 0.f, 0.f, 0.f};
    if (hi1) {
        cur = vr[dir ? 4 : 0];
        if (dir) cur = rev4(cur);
    }

    float hn0 = 0.f, hn1 = 0.f, hn2 = 0.f, hn3 = 0.f, hn4 = 0.f;
    float cp0 = 0.f, cp1 = 0.f, cp2 = 0.f, cp3 = 0.f, cp4 = 0.f;
    float s0, s1, s2, s3;
    float* orow = out + (size_t)seq * TT;

    #pragma unroll 1
    for (int q = 0; q < 5; ++q) {
        const int nq = (q < 4) ? (q + 1) : 4;
        if (hi1) {
            float4 t4v = vr[dir ? (4 - nq) : nq];
            if (dir) t4v = rev4(t4v);
            nxt = t4v;
        }

        STEP(cur.x, s0)
        STEP(cur.y, s1)
        STEP(cur.z, s2)
        STEP(cur.w, s3)

        if (hi1) {
            float4 sv; sv.x = s0; sv.y = s1; sv.z = s2; sv.w = s3;
            *reinterpret_cast<float4*>(orow + q * 4) = sv;
        }
        cur = nxt;
    }

    // ---- masks pass-through: hi0 lanes ----
    if (!hi1) {
        const float* mrow = masks + (size_t)seq * TT;
        float* mout = out + (size_t)BB * TT + (size_t)seq * TT;
        if (dir == 0) {
            const float4* m4 = (const float4*)mrow;
            float4* o4 = (float4*)mout;
            #pragma unroll
            for (int i = 0; i < TT / 4; ++i) o4[i] = m4[i];
        } else {
            #pragma unroll
            for (int t = 0; t < TT; ++t) mout[t] = mrow[TT - 1 - t];
        }
    }
}

extern "C" void kernel_launch(void* const* d_in, const int* in_sizes, int n_in,
                              void* d_out, int out_size, void* d_ws, size_t ws_size,
                              hipStream_t stream) {
    const float* values = (const float*)d_in[0];
    const float* masks  = (const float*)d_in[1];
    const float* W_ih   = (const float*)d_in[2];
    const float* W_hh   = (const float*)d_in[3];
    const float* b_ih   = (const float*)d_in[4];
    const float* b_hh   = (const float*)d_in[5];
    const float* W1     = (const float*)d_in[6];
    const float* b1     = (const float*)d_in[7];
    const float* W2     = (const float*)d_in[8];
    const float* b2     = (const float*)d_in[9];
    const int*   direct = (const int*)d_in[11];
    float* out = (float*)d_out;

    // 32 sequences per wave, 4 waves per block -> 128 seqs/block
    const int block = 256;
    const int grid = BB / 128;   // 2048 blocks -> 8192 waves -> 262144 seqs
    lstm_disc_mfma32<<<grid, block, 0, stream>>>(values, masks, W_ih, W_hh, b_ih, b_hh,
                                                 W1, b1, W2, b2, direct, out);
}

// Round 13
// 59.011 us; speedup vs baseline: 1.7887x; 1.0032x over previous
//
#include <hip/hip_runtime.h>

#define BB 262144
#define TT 20
#define HH 10

static constexpr float L2E = 1.44269504088896340736f;
static constexpr float K2  = 2.0f * L2E;

typedef float    f16v __attribute__((ext_vector_type(16)));
typedef _Float16 h8   __attribute__((ext_vector_type(8)));
typedef __fp16   q2   __attribute__((ext_vector_type(2)));
typedef __fp16   q4   __attribute__((ext_vector_type(4)));
typedef __fp16   q8   __attribute__((ext_vector_type(8)));

#define MFMA32(A, B, C) __builtin_amdgcn_mfma_f32_32x32x16_f16((A), (B), (C), 0, 0, 0)

__device__ __forceinline__ float frcp(float x)  { return __builtin_amdgcn_rcpf(x); }
__device__ __forceinline__ float fexp2(float x) { return __builtin_amdgcn_exp2f(x); }

// Layout identical to R11/R12 (validated, absmax 0.0039):
//   one wave = 32 sequences (C cols). Row r = e + 4*hi_r + 8*q; slot sigma = tile*4+q.
//   hi_r=0: sigma0..4 = units 0..4; hi_r=1: sigma0..4 = units 5..9, sigma5 = head
//   a0..a3, sigma6 = head a4 (e==0). A gate rows prescaled i,f,o: -L2E, g: +2*L2E.
//   B (col=l&31, k=8*(l>>5)+j): k0..9 = h0..h9, k10 = 1, k11 = x, k12..15 = dc (A==0).
//   h5,h6,h7 return to the lo half via 3x shfl_xor(32). All 5 ACT slots are real.
// R13 changes vs R12: waves_per_eu(4,4) -> 128-reg budget (R12's (4,8) forced a
// 64-reg budget and ~2.5x VALU rematerialization bloat); z16 zero-C hoisted out
// of the time loop (materialize 16 zero regs once, not per MFMA per step).

#define ACT(GI, GF, GG, GO, CP, HN) { \
        const float ei  = fexp2(GI); \
        const float ef  = fexp2(GF); \
        const float eg2 = fexp2(GG); \
        const float eo  = fexp2(GO); \
        const float t1 = 1.0f + ef, t2 = 1.0f + ei; \
        const float t3 = eg2 + 1.0f; \
        const float t4k = fmaf(eg2, K2, -K2); \
        const float t5 = t2 * t3; \
        const float cnp = fmaf((CP), t5, t4k * t1) * frcp(t1 * t5); \
        (CP) = cnp; \
        const float ec = fexp2(cnp); \
        (HN) = (ec - 1.0f) * frcp((1.0f + eo) * (ec + 1.0f)); \
    }

#define STEP(XT, SREF) { \
        const float r5 = __shfl_xor(hn0, 32, 64); \
        const float r6 = __shfl_xor(hn1, 32, 64); \
        const float r7 = __shfl_xor(hn2, 32, 64); \
        const float sA = hi1 ? hn3 : hn0; \
        const float sB = hi1 ? hn4 : hn1; \
        const float sC = hi1 ? 1.0f : hn2; \
        const float sD = hi1 ? (XT) : hn3; \
        const q2 p0 = __builtin_amdgcn_cvt_pkrtz(sA, sB); \
        const q2 p1 = __builtin_amdgcn_cvt_pkrtz(sC, sD); \
        const q2 p2 = __builtin_amdgcn_cvt_pkrtz(hn4, r5); \
        const q2 p3 = __builtin_amdgcn_cvt_pkrtz(r6, r7); \
        const q4 lo4 = __builtin_shufflevector(p0, p1, 0, 1, 2, 3); \
        const q4 hi4 = __builtin_shufflevector(p2, p3, 0, 1, 2, 3); \
        const q8 w8  = __builtin_shufflevector(lo4, hi4, 0, 1, 2, 3, 4, 5, 6, 7); \
        const h8 Bf  = __builtin_bit_cast(h8, w8); \
        f16v A0 = MFMA32(Af0, Bf, z16); \
        f16v A1 = MFMA32(Af1, Bf, z16); \
        { \
            float zz = b2p; \
            float u0 = A1[4]; u0 = fmaxf(u0, 0.2f * u0); zz = fmaf(u0, w2p0, zz); \
            float u1 = A1[5]; u1 = fmaxf(u1, 0.2f * u1); zz = fmaf(u1, w2p1, zz); \
            float u2 = A1[6]; u2 = fmaxf(u2, 0.2f * u2); zz = fmaf(u2, w2p2, zz); \
            float u3 = A1[7]; u3 = fmaxf(u3, 0.2f * u3); zz = fmaf(u3, w2p3, zz); \
            float u4 = A1[8]; u4 = fmaxf(u4, 0.2f * u4); zz = fmaf(u4, w2p4, zz); \
            (SREF) = frcp(1.0f + fexp2(zz)); \
        } \
        ACT(A0[0],  A0[1],  A0[2],  A0[3],  cp0, hn0) \
        ACT(A0[4],  A0[5],  A0[6],  A0[7],  cp1, hn1) \
        ACT(A0[8],  A0[9],  A0[10], A0[11], cp2, hn2) \
        ACT(A0[12], A0[13], A0[14], A0[15], cp3, hn3) \
        ACT(A1[0],  A1[1],  A1[2],  A1[3],  cp4, hn4) \
    }

__device__ __forceinline__ float4 rev4(float4 v) {
    float4 r; r.x = v.w; r.y = v.z; r.z = v.y; r.w = v.x; return r;
}

__global__ __launch_bounds__(256)
__attribute__((amdgpu_waves_per_eu(4, 4)))   // 512/4 = 128-reg budget; grid-level
                                             // occupancy measured ~3.2 waves/SIMD,
                                             // so max=4 residency costs nothing
void lstm_disc_mfma32(
    const float* __restrict__ values, const float* __restrict__ masks,
    const float* __restrict__ W_ih, const float* __restrict__ W_hh,
    const float* __restrict__ b_ih, const float* __restrict__ b_hh,
    const float* __restrict__ W1, const float* __restrict__ b1,
    const float* __restrict__ W2, const float* __restrict__ b2,
    const int* __restrict__ directp,
    float* __restrict__ out)
{
    const int tid  = threadIdx.x;
    const int l    = tid & 63;
    const int col  = l & 31;
    const bool hi1 = (l >> 5) != 0;
    const int gw   = blockIdx.x * 4 + (tid >> 6);
    const int seq  = gw * 32 + col;
    const int dir  = *directp;

    // ---- build A fragments once (same as R11/R12) ----
    h8 Af0, Af1;
    {
        const int r    = l & 31;       // A row
        const int e    = r & 3;        // gate index / head row
        const int hi_r = (r >> 2) & 1; // slot half
        const int q    = r >> 3;       // within-tile slot
        const int kb   = (l >> 5) * 8; // k-window base
        h8* afp[2] = {&Af0, &Af1};
        #pragma unroll
        for (int tile = 0; tile < 2; ++tile) {
            const int sig = tile * 4 + q;
            int u;  // >=0: unit; -1: headA; -2: headB; -3: zero row
            if (hi_r == 0) u = (sig <= 4) ? sig : -3;
            else           u = (sig <= 4) ? 5 + sig : ((sig == 5) ? -1 : ((sig == 6) ? -2 : -3));
            float tmp[8];
            #pragma unroll
            for (int j = 0; j < 8; ++j) {
                const int k = kb + j;
                float v = 0.0f;
                if (u >= 0) {
                    const int orow = 10 * e + u;
                    if (k < 10)       v = W_hh[orow * 10 + k];
                    else if (k == 10) v = b_ih[orow] + b_hh[orow];
                    else if (k == 11) v = W_ih[orow];
                    v *= (e == 2) ? (2.0f * L2E) : (-L2E);
                } else if (u == -1) {
                    if (k < 10)       v = W1[e * 10 + k];
                    else if (k == 10) v = b1[e];
                } else if (u == -2) {
                    if (e == 0) {
                        if (k < 10)       v = W1[40 + k];
                        else if (k == 10) v = b1[4];
                    }
                }
                tmp[j] = v;
            }
            h8 a;
            #pragma unroll
            for (int j = 0; j < 8; ++j) a[j] = (_Float16)tmp[j];
            *afp[tile] = a;
        }
    }

    // head scalars, prescaled (wave-uniform -> SGPR)
    const float w2p0 = -L2E * W2[0], w2p1 = -L2E * W2[1], w2p2 = -L2E * W2[2],
                w2p3 = -L2E * W2[3], w2p4 = -L2E * W2[4];
    const float b2p = -L2E * b2[0];

    // zero C-fragment, materialized ONCE (16 regs) -- not per MFMA per step
    const f16v z16 = {0,0,0,0,0,0,0,0,0,0,0,0,0,0,0,0};

    // ---- streamed values: float4 chunks, one-ahead prefetch (hi1 lanes feed x) ----
    const float4* vr = reinterpret_cast<const float4*>(values + (size_t)seq * TT);
    float4 cur = {0.f, 0.f, 0.f, 0.f}, nxt = {0.f, 0.f, 0.f, 0.f};
    if (hi1) {
        cur = vr[dir ? 4 : 0];
        if (dir) cur = rev4(cur);
    }

    float hn0 = 0.f, hn1 = 0.f, hn2 = 0.f, hn3 = 0.f, hn4 = 0.f;
    float cp0 = 0.f, cp1 = 0.f, cp2 = 0.f, cp3 = 0.f, cp4 = 0.f;
    float s0, s1, s2, s3;
    float* orow = out + (size_t)seq * TT;

    #pragma unroll 1
    for (int q = 0; q < 5; ++q) {
        const int nq = (q < 4) ? (q + 1) : 4;
        if (hi1) {
            float4 t4v = vr[dir ? (4 - nq) : nq];
            if (dir) t4v = rev4(t4v);
            nxt = t4v;
        }

        STEP(cur.x, s0)
        STEP(cur.y, s1)
        STEP(cur.z, s2)
        STEP(cur.w, s3)

        if (hi1) {
            float4 sv; sv.x = s0; sv.y = s1; sv.z = s2; sv.w = s3;
            *reinterpret_cast<float4*>(orow + q * 4) = sv;
        }
        cur = nxt;
    }

    // ---- masks pass-through: hi0 lanes ----
    if (!hi1) {
        const float* mrow = masks + (size_t)seq * TT;
        float* mout = out + (size_t)BB * TT + (size_t)seq * TT;
        if (dir == 0) {
            const float4* m4 = (const float4*)mrow;
            float4* o4 = (float4*)mout;
            #pragma unroll
            for (int i = 0; i < TT / 4; ++i) o4[i] = m4[i];
        } else {
            #pragma unroll
            for (int t = 0; t < TT; ++t) mout[t] = mrow[TT - 1 - t];
        }
    }
}

extern "C" void kernel_launch(void* const* d_in, const int* in_sizes, int n_in,
                              void* d_out, int out_size, void* d_ws, size_t ws_size,
                              hipStream_t stream) {
    const float* values = (const float*)d_in[0];
    const float* masks  = (const float*)d_in[1];
    const float* W_ih   = (const float*)d_in[2];
    const float* W_hh   = (const float*)d_in[3];
    const float* b_ih   = (const float*)d_in[4];
    const float* b_hh   = (const float*)d_in[5];
    const float* W1     = (const float*)d_in[6];
    const float* b1     = (const float*)d_in[7];
    const float* W2     = (const float*)d_in[8];
    const float* b2     = (const float*)d_in[9];
    const int*   direct = (const int*)d_in[11];
    float* out = (float*)d_out;

    // 32 sequences per wave, 4 waves per block -> 128 seqs/block
    const int block = 256;
    const int grid = BB / 128;   // 2048 blocks -> 8192 waves -> 262144 seqs
    lstm_disc_mfma32<<<grid, block, 0, stream>>>(values, masks, W_ih, W_hh, b_ih, b_hh,
                                                 W1, b1, W2, b2, direct, out);
}